// Round 1
// baseline (2767.862 us; speedup 1.0000x reference)
//
#include <hip/hip_runtime.h>
#include <math.h>

namespace {
constexpr int NB  = 16;    // batches
constexpr int NP  = 2048;  // points per batch
constexpr int KNN = 32;
constexpr int CH1 = 6;     // 2C
constexpr int CH2 = 32;    // OUT
constexpr float BN_EPS = 1e-5f;

// workspace byte offsets
constexpr size_t OFF_STATS1 = 0;     // double[12]  (sum[6], sumsq[6])
constexpr size_t OFF_STATS2 = 128;   // double[64]  (sum[32], sumsq[32])
constexpr size_t OFF_SC1    = 640;   // float[12]   (scale[6], shift[6])
constexpr size_t OFF_SC2    = 704;   // float[64]   (scale[32], shift[32])
constexpr size_t OFF_P      = 1024;                                  // float[NB*NP*6]
constexpr size_t OFF_Q      = OFF_P    + sizeof(float)*NB*NP*CH1;    // float[NB*NP*6]
constexpr size_t OFF_MINQ   = OFF_Q    + sizeof(float)*NB*NP*CH1;    // float[NB*NP*6]
constexpr size_t OFF_YPRE   = OFF_MINQ + sizeof(float)*NB*NP*CH1;    // float[NB*NP*32]
}

// p_i = b1 + x_i·(W1[0:3]+W1[3:6]) ; q_i = x_i·W1[3:6]
__global__ __launch_bounds__(256) void pq_kernel(const float* __restrict__ x,
                                                 const float* __restrict__ W1,
                                                 const float* __restrict__ b1,
                                                 float* __restrict__ p,
                                                 float* __restrict__ q) {
  const int i = blockIdx.x * 256 + threadIdx.x;  // 0 .. NB*NP-1
  const float x0 = x[i*3+0], x1 = x[i*3+1], x2 = x[i*3+2];
#pragma unroll
  for (int o = 0; o < CH1; ++o) {
    float qv = x0*W1[3*CH1+o] + x1*W1[4*CH1+o] + x2*W1[5*CH1+o];
    float pv = b1[o] + x0*W1[0*CH1+o] + x1*W1[1*CH1+o] + x2*W1[2*CH1+o] + qv;
    p[i*CH1+o] = pv;
    q[i*CH1+o] = qv;
  }
}

// One thread per query point: exact top-K (smallest distance, ties -> smaller index)
// via u64 keys (orderable float bits << 32 | index) kept in a sorted register array.
// Also accumulates BN1 sum/sumsq of (p_i - q_j) and per-channel min_k q_j.
__global__ __launch_bounds__(256) void knn_kernel(const float* __restrict__ x,
                                                  const float* __restrict__ p,
                                                  const float* __restrict__ q,
                                                  float* __restrict__ minq,
                                                  double* __restrict__ stats1) {
  __shared__ float4 pts[NP];  // x,y,z,|x|^2  (32 KiB)
  const int b  = blockIdx.x >> 3;          // 8 blocks per batch
  const int n0 = (blockIdx.x & 7) * 256;
  const float* xb = x + (size_t)b * NP * 3;
  for (int j = threadIdx.x; j < NP; j += 256) {
    float a0 = xb[j*3+0], a1 = xb[j*3+1], a2 = xb[j*3+2];
    float sq = __fadd_rn(__fadd_rn(__fmul_rn(a0,a0), __fmul_rn(a1,a1)), __fmul_rn(a2,a2));
    pts[j] = make_float4(a0, a1, a2, sq);
  }
  __syncthreads();

  const int n = n0 + threadIdx.x;
  const float4 xq = pts[n];

  unsigned long long key[KNN];
#pragma unroll
  for (int k = 0; k < KNN; ++k) key[k] = ~0ull;

  for (int j = 0; j < NP; ++j) {
    float4 pj = pts[j];
    // match reference exactly: sq_i + sq_j - 2*dot, no fma contraction
    float dot = __fadd_rn(__fadd_rn(__fmul_rn(xq.x,pj.x), __fmul_rn(xq.y,pj.y)), __fmul_rn(xq.z,pj.z));
    float d   = __fsub_rn(__fadd_rn(xq.w, pj.w), __fmul_rn(2.0f, dot));
    unsigned int db = __float_as_uint(d);
    db ^= ((unsigned int)((int)db >> 31)) | 0x80000000u;  // orderable bits
    unsigned long long kk = (((unsigned long long)db) << 32) | (unsigned int)j;
    if (kk < key[KNN-1]) {
#pragma unroll
      for (int s = 0; s < KNN; ++s) {   // sorted insert, static indices only
        bool lt = kk < key[s];
        unsigned long long lo = lt ? kk : key[s];
        kk     = lt ? key[s] : kk;
        key[s] = lo;
      }
    }
  }

  const int qi = b * NP + n;
  float pv[CH1], mq[CH1], sum[CH1], ssq[CH1];
#pragma unroll
  for (int c = 0; c < CH1; ++c) { pv[c] = p[qi*CH1+c]; mq[c] = INFINITY; sum[c] = 0.f; ssq[c] = 0.f; }
#pragma unroll 4
  for (int k = 0; k < KNN; ++k) {
    int j = (int)(key[k] & 0xFFFFFFFFu);
    const float* qj = q + ((size_t)b * NP + j) * CH1;
#pragma unroll
    for (int c = 0; c < CH1; ++c) {
      float qv = qj[c];
      float h  = pv[c] - qv;
      sum[c] += h; ssq[c] += h*h;
      mq[c] = fminf(mq[c], qv);
    }
  }
#pragma unroll
  for (int c = 0; c < CH1; ++c) minq[qi*CH1+c] = mq[c];

#pragma unroll
  for (int c = 0; c < CH1; ++c) {
    float s = sum[c], s2 = ssq[c];
    for (int off = 32; off; off >>= 1) { s += __shfl_down(s, off); s2 += __shfl_down(s2, off); }
    if ((threadIdx.x & 63) == 0) {
      atomicAdd(stats1 + c,       (double)s);
      atomicAdd(stats1 + CH1 + c, (double)s2);
    }
  }
}

__global__ void finalize_kernel(const double* __restrict__ stats,
                                const float* __restrict__ gamma,
                                const float* __restrict__ beta,
                                float* __restrict__ sc, int nch, long long cnt) {
  int o = threadIdx.x;
  if (o < nch) {
    double mean = stats[o] / (double)cnt;
    double var  = stats[nch + o] / (double)cnt - mean * mean;
    float vf    = (float)var + BN_EPS;
    float scale = gamma[o] / sqrtf(vf);
    sc[o]       = scale;
    sc[nch + o] = beta[o] - (float)mean * scale;
  }
}

// max_k ELU(affine(p - q_j)) == ELU(affine(p - min_k q_j)) since scale>0 and ELU monotone.
__global__ __launch_bounds__(256) void stage2_kernel(const float* __restrict__ p,
                                                     const float* __restrict__ minq,
                                                     const float* __restrict__ sc1,
                                                     const float* __restrict__ W2,
                                                     const float* __restrict__ b2,
                                                     float* __restrict__ ypre,
                                                     double* __restrict__ stats2) {
  const int qi = blockIdx.x * 256 + threadIdx.x;  // 0 .. NB*NP-1
  float me[CH1];
#pragma unroll
  for (int c = 0; c < CH1; ++c) {
    float m = p[qi*CH1+c] - minq[qi*CH1+c];
    float t = sc1[c] * m + sc1[CH1+c];
    me[c] = t > 0.f ? t : expm1f(t);
  }
#pragma unroll
  for (int o = 0; o < CH2; ++o) {
    float y = b2[o];
#pragma unroll
    for (int c = 0; c < CH1; ++c) y += me[c] * W2[c*CH2+o];
    ypre[(size_t)qi*CH2 + o] = y;
    float s = y, s2 = y*y;
    for (int off = 32; off; off >>= 1) { s += __shfl_down(s, off); s2 += __shfl_down(s2, off); }
    if ((threadIdx.x & 63) == 0) {
      atomicAdd(stats2 + o,       (double)s);
      atomicAdd(stats2 + CH2 + o, (double)s2);
    }
  }
}

__global__ __launch_bounds__(256) void out_kernel(const float* __restrict__ ypre,
                                                  const float* __restrict__ sc2,
                                                  float* __restrict__ out) {
  const int i = blockIdx.x * 256 + threadIdx.x;  // 0 .. NB*NP*CH2-1
  const int o = i & (CH2 - 1);
  float t = sc2[o] * ypre[i] + sc2[CH2 + o];
  out[i] = t > 0.f ? t : expm1f(t);
}

extern "C" void kernel_launch(void* const* d_in, const int* in_sizes, int n_in,
                              void* d_out, int out_size, void* d_ws, size_t ws_size,
                              hipStream_t stream) {
  const float* x      = (const float*)d_in[0];
  const float* W1     = (const float*)d_in[1];
  const float* b1     = (const float*)d_in[2];
  const float* gamma1 = (const float*)d_in[3];
  const float* beta1  = (const float*)d_in[4];
  const float* W2     = (const float*)d_in[5];
  const float* b2     = (const float*)d_in[6];
  const float* gamma2 = (const float*)d_in[7];
  const float* beta2  = (const float*)d_in[8];
  float* out = (float*)d_out;
  char* ws = (char*)d_ws;

  double* stats1 = (double*)(ws + OFF_STATS1);
  double* stats2 = (double*)(ws + OFF_STATS2);
  float* sc1  = (float*)(ws + OFF_SC1);
  float* sc2  = (float*)(ws + OFF_SC2);
  float* p    = (float*)(ws + OFF_P);
  float* q    = (float*)(ws + OFF_Q);
  float* minq = (float*)(ws + OFF_MINQ);
  float* ypre = (float*)(ws + OFF_YPRE);

  hipMemsetAsync(ws, 0, 640, stream);  // zero BN stat accumulators (graph-capture safe)

  pq_kernel   <<<dim3(NB*NP/256), dim3(256), 0, stream>>>(x, W1, b1, p, q);
  knn_kernel  <<<dim3(NB*NP/256), dim3(256), 0, stream>>>(x, p, q, minq, stats1);
  finalize_kernel<<<dim3(1), dim3(64), 0, stream>>>(stats1, gamma1, beta1, sc1, CH1, (long long)NB*NP*KNN);
  stage2_kernel<<<dim3(NB*NP/256), dim3(256), 0, stream>>>(p, minq, sc1, W2, b2, ypre, stats2);
  finalize_kernel<<<dim3(1), dim3(64), 0, stream>>>(stats2, gamma2, beta2, sc2, CH2, (long long)NB*NP);
  out_kernel  <<<dim3(NB*NP*CH2/256), dim3(256), 0, stream>>>(ypre, sc2, out);
}

// Round 2
// 145.352 us; speedup vs baseline: 19.0424x; 19.0424x over previous
//
#include <hip/hip_runtime.h>
#include <math.h>

namespace {
constexpr int NB = 16, NP = 2048, KNN = 32, CH1 = 6, CH2 = 32;
constexpr float BN_EPS = 1e-5f;

// workspace byte offsets
constexpr size_t OFF_STATS1 = 0;      // double[12]  (sum[6], sumsq[6])
constexpr size_t OFF_STATS2 = 128;    // double[64]  (sum[32], sumsq[32])
constexpr size_t OFF_SC1    = 768;    // float[12]
constexpr size_t OFF_SC2    = 832;    // float[64]
constexpr size_t OFF_P      = 4096;                                   // float[NB*NP*6]
constexpr size_t OFF_Q      = OFF_P     + sizeof(float)*NB*NP*CH1;    // float[NB*NP*6]
constexpr size_t OFF_SUMQ   = OFF_Q     + sizeof(float)*NB*NP*CH1;    // float[NB*NP*6]
constexpr size_t OFF_SUMQQ  = OFF_SUMQ  + sizeof(float)*NB*NP*CH1;    // float[NB*NP*6]
constexpr size_t OFF_MINQ   = OFF_SUMQQ + sizeof(float)*NB*NP*CH1;    // float[NB*NP*6]
}

// ---------------- DPP wave-64 reductions (VALU pipe, no LDS) ----------------
template <int C> __device__ __forceinline__ int dpp0i(int x) {
  return __builtin_amdgcn_update_dpp(0, x, C, 0xf, 0xf, true);   // invalid lanes -> 0
}
template <int C> __device__ __forceinline__ float dpp0f(float x) {
  return __uint_as_float((unsigned)__builtin_amdgcn_update_dpp(
      0, (int)__float_as_uint(x), C, 0xf, 0xf, true));
}
template <int C> __device__ __forceinline__ float dppInff(float x) {
  return __uint_as_float((unsigned)__builtin_amdgcn_update_dpp(
      0x7F800000, (int)__float_as_uint(x), C, 0xf, 0xf, false)); // invalid lanes -> +INF
}
// full-wave sum, result broadcast (scalar) to all lanes
__device__ __forceinline__ int wave_isum_bcast(int x) {
  x += dpp0i<0x111>(x); x += dpp0i<0x112>(x); x += dpp0i<0x114>(x);
  x += dpp0i<0x118>(x); x += dpp0i<0x142>(x); x += dpp0i<0x143>(x);
  return __builtin_amdgcn_readlane(x, 63);
}
// full-wave sum/min; result valid in lane 63 only
__device__ __forceinline__ float wave_fsum63(float x) {
  x += dpp0f<0x111>(x); x += dpp0f<0x112>(x); x += dpp0f<0x114>(x);
  x += dpp0f<0x118>(x); x += dpp0f<0x142>(x); x += dpp0f<0x143>(x);
  return x;
}
__device__ __forceinline__ float wave_fmin63(float x) {
  x = fminf(x, dppInff<0x111>(x)); x = fminf(x, dppInff<0x112>(x));
  x = fminf(x, dppInff<0x114>(x)); x = fminf(x, dppInff<0x118>(x));
  x = fminf(x, dppInff<0x142>(x)); x = fminf(x, dppInff<0x143>(x));
  return x;
}

// exact reference distance: sq_i + sq_j - 2*dot, no fma contraction; orderable bits
__device__ __forceinline__ unsigned dist_bits(float4 xq, float4 pj) {
  float dot = __fadd_rn(__fadd_rn(__fmul_rn(xq.x, pj.x), __fmul_rn(xq.y, pj.y)),
                        __fmul_rn(xq.z, pj.z));
  float d = __fsub_rn(__fadd_rn(xq.w, pj.w), __fmul_rn(2.0f, dot));
  unsigned db = __float_as_uint(d);
  db ^= ((unsigned)((int)db >> 31)) | 0x80000000u;
  return db;
}

// p_i = b1 + x_i·(W1[0:3]+W1[3:6]) ; q_i = x_i·W1[3:6]
__global__ __launch_bounds__(256) void pq_kernel(const float* __restrict__ x,
                                                 const float* __restrict__ W1,
                                                 const float* __restrict__ b1,
                                                 float* __restrict__ p,
                                                 float* __restrict__ q) {
  const int i = blockIdx.x * 256 + threadIdx.x;
  const float x0 = x[i * 3 + 0], x1 = x[i * 3 + 1], x2 = x[i * 3 + 2];
#pragma unroll
  for (int o = 0; o < CH1; ++o) {
    float qv = x0 * W1[3 * CH1 + o] + x1 * W1[4 * CH1 + o] + x2 * W1[5 * CH1 + o];
    float pv = b1[o] + x0 * W1[0 * CH1 + o] + x1 * W1[1 * CH1 + o] + x2 * W1[2 * CH1 + o] + qv;
    p[i * CH1 + o] = pv;
    q[i * CH1 + o] = qv;
  }
}

// One WAVE per query. 64 lanes x 32 slots cover the 2048 candidates.
// Exact top-32 by (distance bits, index) via bit-plane radix select.
__global__ __launch_bounds__(256, 5) void knn_kernel(const float* __restrict__ x,
                                                     const float* __restrict__ q,
                                                     float* __restrict__ sumq,
                                                     float* __restrict__ sumqq,
                                                     float* __restrict__ minq) {
  __shared__ float4 pts[NP];  // 32 KiB, shared by the block's 4 waves (same batch)
  const int lane = threadIdx.x & 63;
  const int w    = threadIdx.x >> 6;
  const int qi0  = blockIdx.x * 4;        // 4 queries per block, same batch (4 | 2048)
  const int b    = qi0 >> 11;
  const int qi   = qi0 + w;
  const int n    = qi & (NP - 1);

  const float* xb = x + (size_t)b * NP * 3;
  for (int j = threadIdx.x; j < NP; j += 256) {
    float a0 = xb[j * 3 + 0], a1 = xb[j * 3 + 1], a2 = xb[j * 3 + 2];
    float sq = __fadd_rn(__fadd_rn(__fmul_rn(a0, a0), __fmul_rn(a1, a1)), __fmul_rn(a2, a2));
    pts[j] = make_float4(a0, a1, a2, sq);
  }
  __syncthreads();

  const float4 xq = pts[n];

  // distances for slots t: candidate j = t*64 + lane.  Store reversed (a[31-t])
  // so that after transpose32, plane for db-bit B is a[31-B] with bit v <-> slot v.
  unsigned a[32];
#pragma unroll
  for (int t = 0; t < 32; ++t) a[31 - t] = dist_bits(xq, pts[t * 64 + lane]);

  // in-register 32x32 bit transpose (Hacker's Delight)
#define TSTAGE(J, M)                                        \
  _Pragma("unroll") for (int g = 0; g < 16; ++g) {          \
    const int k = ((g / (J)) * 2 * (J)) + (g % (J));        \
    unsigned t = (a[k] ^ (a[k + (J)] >> (J))) & (M);        \
    a[k] ^= t; a[k + (J)] ^= t << (J);                      \
  }
  TSTAGE(16, 0x0000FFFFu)
  TSTAGE(8,  0x00FF00FFu)
  TSTAGE(4,  0x0F0F0F0Fu)
  TSTAGE(2,  0x33333333u)
  TSTAGE(1,  0x55555555u)
#undef TSTAGE

  // radix select on high 16 distance bits (planes a[0..15] = bits 31..16)
  unsigned alive = 0xFFFFFFFFu, below = 0u;
  int rem = KNN;
#pragma unroll
  for (int i = 0; i < 16; ++i) {
    unsigned zeros = alive & ~a[i];
    int c0 = wave_isum_bcast(__popc(zeros));   // uniform
    if (c0 >= rem) {
      alive = zeros;
    } else {
      rem -= c0;
      below |= zeros;
      alive &= a[i];
    }
  }

  unsigned sel = below;
  int ca = wave_isum_bcast(__popc(alive));
  if (ca == rem) {
    sel |= alive;             // common case: the tie bucket fits exactly
  } else {
    // pull `rem` smallest (full db, then index) from the equal-prefix bucket
    for (int it = 0; it < rem; ++it) {
      unsigned long long best = ~0ull;
      unsigned mm = alive;
      while (mm) {
        int v = __builtin_ctz(mm); mm &= mm - 1;
        int j = (v << 6) | lane;
        unsigned db = dist_bits(xq, pts[j]);
        unsigned long long kk = (((unsigned long long)db) << 32) | (unsigned)j;
        best = kk < best ? kk : best;
      }
#pragma unroll
      for (int off = 1; off < 64; off <<= 1) {
        unsigned long long o = __shfl_xor(best, off, 64);
        best = o < best ? o : best;
      }
      int jwin = (int)(best & 0xFFFFFFFFull);
      if ((jwin & 63) == lane) {
        unsigned bit = 1u << (jwin >> 6);
        alive &= ~bit;
        sel |= bit;
      }
    }
  }

  // accumulate per-query sum(q), sum(q^2), min(q) over the 32 selected neighbors
  float sq[CH1], sqq[CH1], mn[CH1];
#pragma unroll
  for (int c = 0; c < CH1; ++c) { sq[c] = 0.f; sqq[c] = 0.f; mn[c] = INFINITY; }
  const float* qb = q + (size_t)b * NP * CH1;
  unsigned m = sel;
  while (m) {
    int v = __builtin_ctz(m); m &= m - 1;
    int j = (v << 6) | lane;
    const float* qj = qb + (size_t)j * CH1;
#pragma unroll
    for (int c = 0; c < CH1; ++c) {
      float qv = qj[c];
      sq[c] += qv; sqq[c] += qv * qv; mn[c] = fminf(mn[c], qv);
    }
  }
#pragma unroll
  for (int c = 0; c < CH1; ++c) {
    float s  = wave_fsum63(sq[c]);
    float s2 = wave_fsum63(sqq[c]);
    float mmn = wave_fmin63(mn[c]);
    if (lane == 63) {
      sumq [qi * CH1 + c] = s;
      sumqq[qi * CH1 + c] = s2;
      minq [qi * CH1 + c] = mmn;
    }
  }
}

// BN1 global stats from per-query partials: sum_k h = K*p - sum(q);  sum_k h^2 = K*p^2 - 2p*sum(q) + sum(q^2)
__global__ __launch_bounds__(256) void reduce1_kernel(const float* __restrict__ p,
                                                      const float* __restrict__ sumq,
                                                      const float* __restrict__ sumqq,
                                                      double* __restrict__ stats1) {
  const int qi = blockIdx.x * 256 + threadIdx.x;
  const int lane = threadIdx.x & 63;
#pragma unroll
  for (int c = 0; c < CH1; ++c) {
    float pv = p[qi * CH1 + c];
    float s  = sumq[qi * CH1 + c];
    float s2 = sumqq[qi * CH1 + c];
    float hs = 32.f * pv - s;
    float hq = 32.f * pv * pv - 2.f * pv * s + s2;
    float ws_ = wave_fsum63(hs);
    float wq  = wave_fsum63(hq);
    if (lane == 63) {
      atomicAdd(stats1 + c,        (double)ws_);
      atomicAdd(stats1 + CH1 + c,  (double)wq);
    }
  }
}

__global__ void finalize_kernel(const double* __restrict__ stats,
                                const float* __restrict__ gamma,
                                const float* __restrict__ beta,
                                float* __restrict__ sc, int nch, long long cnt) {
  int o = threadIdx.x;
  if (o < nch) {
    double mean = stats[o] / (double)cnt;
    double var  = stats[nch + o] / (double)cnt - mean * mean;
    float vf    = (float)var + BN_EPS;
    float scale = gamma[o] / sqrtf(vf);
    sc[o]       = scale;
    sc[nch + o] = beta[o] - (float)mean * scale;
  }
}

// max_k ELU(affine(p - q_j)) == ELU(affine(p - min_k q_j))  (scale>0, ELU monotone)
__global__ __launch_bounds__(256) void stage2_kernel(const float* __restrict__ p,
                                                     const float* __restrict__ minq,
                                                     const float* __restrict__ sc1,
                                                     const float* __restrict__ W2,
                                                     const float* __restrict__ b2,
                                                     double* __restrict__ stats2) {
  __shared__ float rs[4][CH2], rq[4][CH2];
  const int qi = blockIdx.x * 256 + threadIdx.x;
  const int w = threadIdx.x >> 6, lane = threadIdx.x & 63;
  float me[CH1];
#pragma unroll
  for (int c = 0; c < CH1; ++c) {
    float mval = p[qi * CH1 + c] - minq[qi * CH1 + c];
    float t = fmaf(sc1[c], mval, sc1[CH1 + c]);
    me[c] = t > 0.f ? t : expm1f(t);
  }
#pragma unroll
  for (int o = 0; o < CH2; ++o) {
    float y = b2[o];
#pragma unroll
    for (int c = 0; c < CH1; ++c) y = fmaf(me[c], W2[c * CH2 + o], y);
    float s  = wave_fsum63(y);
    float s2 = wave_fsum63(y * y);
    if (lane == 63) { rs[w][o] = s; rq[w][o] = s2; }
  }
  __syncthreads();
  if (threadIdx.x < CH2) {
    int o = threadIdx.x;
    atomicAdd(stats2 + o, (double)((rs[0][o] + rs[1][o]) + (rs[2][o] + rs[3][o])));
  } else if (threadIdx.x < 2 * CH2) {
    int o = threadIdx.x - CH2;
    atomicAdd(stats2 + CH2 + o, (double)((rq[0][o] + rq[1][o]) + (rq[2][o] + rq[3][o])));
  }
}

__global__ __launch_bounds__(256) void out_kernel(const float* __restrict__ p,
                                                  const float* __restrict__ minq,
                                                  const float* __restrict__ sc1,
                                                  const float* __restrict__ W2,
                                                  const float* __restrict__ b2,
                                                  const float* __restrict__ sc2,
                                                  float* __restrict__ out) {
  const int qi = blockIdx.x * 256 + threadIdx.x;
  float me[CH1];
#pragma unroll
  for (int c = 0; c < CH1; ++c) {
    float mval = p[qi * CH1 + c] - minq[qi * CH1 + c];
    float t = fmaf(sc1[c], mval, sc1[CH1 + c]);
    me[c] = t > 0.f ? t : expm1f(t);
  }
#pragma unroll
  for (int o = 0; o < CH2; ++o) {
    float y = b2[o];
#pragma unroll
    for (int c = 0; c < CH1; ++c) y = fmaf(me[c], W2[c * CH2 + o], y);
    float t = fmaf(sc2[o], y, sc2[CH2 + o]);
    out[(size_t)qi * CH2 + o] = t > 0.f ? t : expm1f(t);
  }
}

extern "C" void kernel_launch(void* const* d_in, const int* in_sizes, int n_in,
                              void* d_out, int out_size, void* d_ws, size_t ws_size,
                              hipStream_t stream) {
  const float* x      = (const float*)d_in[0];
  const float* W1     = (const float*)d_in[1];
  const float* b1     = (const float*)d_in[2];
  const float* gamma1 = (const float*)d_in[3];
  const float* beta1  = (const float*)d_in[4];
  const float* W2     = (const float*)d_in[5];
  const float* b2     = (const float*)d_in[6];
  const float* gamma2 = (const float*)d_in[7];
  const float* beta2  = (const float*)d_in[8];
  float* out = (float*)d_out;
  char* ws = (char*)d_ws;

  double* stats1 = (double*)(ws + OFF_STATS1);
  double* stats2 = (double*)(ws + OFF_STATS2);
  float* sc1   = (float*)(ws + OFF_SC1);
  float* sc2   = (float*)(ws + OFF_SC2);
  float* p     = (float*)(ws + OFF_P);
  float* q     = (float*)(ws + OFF_Q);
  float* sumq  = (float*)(ws + OFF_SUMQ);
  float* sumqq = (float*)(ws + OFF_SUMQQ);
  float* minq  = (float*)(ws + OFF_MINQ);

  hipMemsetAsync(ws, 0, 640, stream);  // zero BN stat accumulators

  pq_kernel     <<<dim3(NB * NP / 256), dim3(256), 0, stream>>>(x, W1, b1, p, q);
  knn_kernel    <<<dim3(NB * NP / 4),   dim3(256), 0, stream>>>(x, q, sumq, sumqq, minq);
  reduce1_kernel<<<dim3(NB * NP / 256), dim3(256), 0, stream>>>(p, sumq, sumqq, stats1);
  finalize_kernel<<<dim3(1), dim3(64), 0, stream>>>(stats1, gamma1, beta1, sc1, CH1,
                                                    (long long)NB * NP * KNN);
  stage2_kernel <<<dim3(NB * NP / 256), dim3(256), 0, stream>>>(p, minq, sc1, W2, b2, stats2);
  finalize_kernel<<<dim3(1), dim3(64), 0, stream>>>(stats2, gamma2, beta2, sc2, CH2,
                                                    (long long)NB * NP);
  out_kernel    <<<dim3(NB * NP / 256), dim3(256), 0, stream>>>(p, minq, sc1, W2, b2, sc2, out);
}

// Round 3
// 79.064 us; speedup vs baseline: 35.0079x; 1.8384x over previous
//
#include <hip/hip_runtime.h>
#include <math.h>

namespace {
constexpr int NB = 16, NP = 2048, KNN = 32, CH1 = 6, CH2 = 32;
constexpr int NBLK = NB * NP / 8;   // 4096 knn blocks (8 queries each)
constexpr float BN_EPS = 1e-5f;

// workspace byte offsets
constexpr size_t OFF_STATS2 = 0;       // double[64] (sum[32], sumsq[32])
constexpr size_t OFF_SC1    = 512;     // float[12]
constexpr size_t OFF_P      = 1024;                                 // float[NB*NP*6]
constexpr size_t OFF_MINQ   = OFF_P    + sizeof(float)*NB*NP*CH1;   // float[NB*NP*6]
constexpr size_t OFF_PART   = OFF_MINQ + sizeof(float)*NB*NP*CH1;   // float[12*NBLK]
}

// ---------------- DPP wave-64 reductions (VALU pipe, no LDS) ----------------
template <int C> __device__ __forceinline__ int dpp0i(int x) {
  return __builtin_amdgcn_update_dpp(0, x, C, 0xf, 0xf, true);
}
template <int C> __device__ __forceinline__ float dpp0f(float x) {
  return __uint_as_float((unsigned)__builtin_amdgcn_update_dpp(
      0, (int)__float_as_uint(x), C, 0xf, 0xf, true));
}
template <int C> __device__ __forceinline__ float dppInff(float x) {
  return __uint_as_float((unsigned)__builtin_amdgcn_update_dpp(
      0x7F800000, (int)__float_as_uint(x), C, 0xf, 0xf, false));
}
__device__ __forceinline__ int wave_isum_bcast(int x) {
  x += dpp0i<0x111>(x); x += dpp0i<0x112>(x); x += dpp0i<0x114>(x);
  x += dpp0i<0x118>(x); x += dpp0i<0x142>(x); x += dpp0i<0x143>(x);
  return __builtin_amdgcn_readlane(x, 63);
}
__device__ __forceinline__ float wave_fsum63(float x) {
  x += dpp0f<0x111>(x); x += dpp0f<0x112>(x); x += dpp0f<0x114>(x);
  x += dpp0f<0x118>(x); x += dpp0f<0x142>(x); x += dpp0f<0x143>(x);
  return x;
}
__device__ __forceinline__ float wave_fmin63(float x) {
  x = fminf(x, dppInff<0x111>(x)); x = fminf(x, dppInff<0x112>(x));
  x = fminf(x, dppInff<0x114>(x)); x = fminf(x, dppInff<0x118>(x));
  x = fminf(x, dppInff<0x142>(x)); x = fminf(x, dppInff<0x143>(x));
  return x;
}

#define BSEL(m, x, y) ((((x)) & (m)) | (((y)) & ~(m)))  // per-bit m ? x : y

// Fused: pq + KNN select + per-query min(q) + BN1 block partials.
// One WAVE per query; 8 waves/block share one staged batch tile.
__global__ __launch_bounds__(512, 6) void knn_kernel(const float* __restrict__ x,
                                                     const float* __restrict__ W1,
                                                     const float* __restrict__ b1,
                                                     float* __restrict__ pout,
                                                     float* __restrict__ minq,
                                                     float* __restrict__ part) {
  __shared__ float4 pts[NP];      // x,y,z,|x|^2 (32 KiB)
  __shared__ float red[12][8];
  const int lane = threadIdx.x & 63;
  const int w    = threadIdx.x >> 6;
  const int qi   = blockIdx.x * 8 + w;     // 8 | 2048 -> same batch per block
  const int b    = qi >> 11;
  const int n    = qi & (NP - 1);

  const float* xb = x + (size_t)b * NP * 3;
  for (int j = threadIdx.x; j < NP; j += 512) {
    float a0 = xb[j*3+0], a1 = xb[j*3+1], a2 = xb[j*3+2];
    float sq = __fadd_rn(__fadd_rn(__fmul_rn(a0,a0), __fmul_rn(a1,a1)), __fmul_rn(a2,a2));
    pts[j] = make_float4(a0, a1, a2, sq);
  }
  __syncthreads();

  const float4 xq = pts[n];

  // distances (bit-exact vs reference formula); all d >= 0 for this data, so
  // orderable bits = db | 0x80000000 and the constant bit-31 plane is skipped.
  unsigned a[32];
#pragma unroll
  for (int t = 0; t < 32; ++t) {
    float4 pj = pts[t*64 + lane];
    float dot = __fadd_rn(__fadd_rn(__fmul_rn(xq.x,pj.x), __fmul_rn(xq.y,pj.y)),
                          __fmul_rn(xq.z,pj.z));
    float d = __fsub_rn(__fadd_rn(xq.w, pj.w), __fmul_rn(2.0f, dot));
    a[31 - t] = __float_as_uint(d) | 0x80000000u;
  }

  // 32x32 bit transpose: v_perm for byte-granular stages, bfi for sub-byte.
#pragma unroll
  for (int g = 0; g < 16; ++g) {      // J=16
    unsigned hi = a[g], lo = a[g+16];
    a[g]    = __builtin_amdgcn_perm(hi, lo, 0x07060302u);
    a[g+16] = __builtin_amdgcn_perm(hi, lo, 0x05040100u);
  }
#pragma unroll
  for (int g = 0; g < 16; ++g) {      // J=8
    int k = (g >> 3)*16 + (g & 7);
    unsigned hi = a[k], lo = a[k+8];
    a[k]   = __builtin_amdgcn_perm(hi, lo, 0x07030501u);
    a[k+8] = __builtin_amdgcn_perm(hi, lo, 0x06020400u);
  }
#pragma unroll
  for (int g = 0; g < 16; ++g) {      // J=4
    int k = (g >> 2)*8 + (g & 3);
    unsigned A = a[k], B = a[k+4];
    a[k]   = BSEL(0x0F0F0F0Fu, B >> 4, A);
    a[k+4] = BSEL(0xF0F0F0F0u, A << 4, B);
  }
#pragma unroll
  for (int g = 0; g < 16; ++g) {      // J=2
    int k = (g >> 1)*4 + (g & 1);
    unsigned A = a[k], B = a[k+2];
    a[k]   = BSEL(0x33333333u, B >> 2, A);
    a[k+2] = BSEL(0xCCCCCCCCu, A << 2, B);
  }
#pragma unroll
  for (int g = 0; g < 16; ++g) {      // J=1
    int k = g*2;
    unsigned A = a[k], B = a[k+1];
    a[k]   = BSEL(0x55555555u, B >> 1, A);
    a[k+1] = BSEL(0xAAAAAAAAu, A << 1, B);
  }
  // plane a[i] = distance bit (31-i); bit v of a plane <-> candidate v*64+lane

  // radix select, planes 1..15 (bits 30..16)
  unsigned alive = 0xFFFFFFFFu, below = 0u;
  int rem = KNN;
#pragma unroll
  for (int i = 1; i <= 15; ++i) {
    unsigned zeros = alive & ~a[i];
    int c0 = wave_isum_bcast(__popc(zeros));
    if (c0 >= rem) alive = zeros;
    else { rem -= c0; below |= zeros; alive &= a[i]; }
  }
  int ca = wave_isum_bcast(__popc(alive));
  // extend onto low planes only while unresolved (scalar-guarded)
#pragma unroll
  for (int i = 16; i < 32; ++i) {
    if (ca != rem) {
      unsigned zeros = alive & ~a[i];
      int c0 = wave_isum_bcast(__popc(zeros));
      if (c0 >= rem) { alive = zeros; ca = c0; }
      else { rem -= c0; below |= zeros; alive &= a[i]; ca -= c0; }
    }
  }
  unsigned sel = below;
  if (ca == rem) {
    sel |= alive;
  } else {
    // bit-identical distances: take smallest indices j = v*64+lane (v-major)
    for (int v = 0; v < 32; ++v) {
      if (rem <= 0) break;
      bool mine = (alive >> v) & 1;
      unsigned long long m = __ballot(mine);
      int c = __popcll(m);
      if (c <= rem) { if (mine) sel |= 1u << v; rem -= c; }
      else {
        if (mine && (int)__popcll(m & ((1ull << lane) - 1)) < rem) sel |= 1u << v;
        rem = 0;
      }
    }
  }

  // gather: sum/sumsq/min of q_j over selected neighbors (q from LDS pts + SGPR W1)
  float sq_[CH1], sqq[CH1], mn[CH1];
#pragma unroll
  for (int c = 0; c < CH1; ++c) { sq_[c] = 0.f; sqq[c] = 0.f; mn[c] = INFINITY; }
  unsigned m = sel;
  while (m) {
    int v = __builtin_ctz(m); m &= m - 1;
    float4 pj = pts[(v << 6) | lane];
#pragma unroll
    for (int c = 0; c < CH1; ++c) {
      float qv = pj.x*W1[3*CH1+c] + pj.y*W1[4*CH1+c] + pj.z*W1[5*CH1+c];
      sq_[c] += qv; sqq[c] += qv*qv; mn[c] = fminf(mn[c], qv);
    }
  }

  // p_i for this query (uniform across lanes)
  float pv[CH1];
#pragma unroll
  for (int c = 0; c < CH1; ++c) {
    float qv = xq.x*W1[3*CH1+c] + xq.y*W1[4*CH1+c] + xq.z*W1[5*CH1+c];
    pv[c] = b1[c] + xq.x*W1[c] + xq.y*W1[CH1+c] + xq.z*W1[2*CH1+c] + qv;
  }

#pragma unroll
  for (int c = 0; c < CH1; ++c) {
    float s  = wave_fsum63(sq_[c]);
    float s2 = wave_fsum63(sqq[c]);
    float mm = wave_fmin63(mn[c]);
    if (lane == 63) {
      minq[qi*CH1 + c] = mm;
      float hs = fmaf(32.f, pv[c], -s);                                 // sum_k (p - q)
      float hq = fmaf(32.f, pv[c]*pv[c], fmaf(-2.f*pv[c], s, s2));      // sum_k (p - q)^2
      red[c][w] = hs; red[CH1 + c][w] = hq;
    }
  }
  if (lane == 0) {
#pragma unroll
    for (int c = 0; c < CH1; ++c) pout[qi*CH1 + c] = pv[c];
  }
  __syncthreads();
  if (threadIdx.x < 12) {
    float s = 0.f;
#pragma unroll
    for (int ww = 0; ww < 8; ++ww) s += red[threadIdx.x][ww];
    part[threadIdx.x * NBLK + blockIdx.x] = s;
  }
}

// single block: reduce 12 x NBLK partials and produce sc1 (scale/shift)
__global__ __launch_bounds__(768) void reduce_fin1_kernel(const float* __restrict__ part,
                                                          const float* __restrict__ gamma1,
                                                          const float* __restrict__ beta1,
                                                          float* __restrict__ sc1) {
  __shared__ float tot[12];
  const int lane = threadIdx.x & 63, w = threadIdx.x >> 6;  // 12 waves, one stat each
  float s = 0.f;
  for (int it = 0; it < NBLK / 64; ++it) s += part[w * NBLK + it * 64 + lane];
  s = wave_fsum63(s);
  if (lane == 63) tot[w] = s;
  __syncthreads();
  if (threadIdx.x < CH1) {
    int c = threadIdx.x;
    double cnt  = (double)NB * NP * KNN;
    double mean = (double)tot[c] / cnt;
    double var  = (double)tot[CH1 + c] / cnt - mean * mean;
    float vf    = (float)var + BN_EPS;
    float scale = gamma1[c] / sqrtf(vf);
    sc1[c]        = scale;
    sc1[CH1 + c]  = beta1[c] - (float)mean * scale;
  }
}

// max_k ELU(affine(p - q_j)) == ELU(affine(p - min_k q_j)) ; accumulate BN2 stats
__global__ __launch_bounds__(256) void stage2_kernel(const float* __restrict__ p,
                                                     const float* __restrict__ minq,
                                                     const float* __restrict__ sc1,
                                                     const float* __restrict__ W2,
                                                     const float* __restrict__ b2,
                                                     double* __restrict__ stats2) {
  __shared__ float rs[4][CH2], rq[4][CH2];
  const int qi = blockIdx.x * 256 + threadIdx.x;
  const int w = threadIdx.x >> 6, lane = threadIdx.x & 63;
  float me[CH1];
#pragma unroll
  for (int c = 0; c < CH1; ++c) {
    float mval = p[qi*CH1 + c] - minq[qi*CH1 + c];
    float t = fmaf(sc1[c], mval, sc1[CH1 + c]);
    me[c] = t > 0.f ? t : expm1f(t);
  }
#pragma unroll
  for (int o = 0; o < CH2; ++o) {
    float y = b2[o];
#pragma unroll
    for (int c = 0; c < CH1; ++c) y = fmaf(me[c], W2[c*CH2 + o], y);
    float s  = wave_fsum63(y);
    float s2 = wave_fsum63(y * y);
    if (lane == 63) { rs[w][o] = s; rq[w][o] = s2; }
  }
  __syncthreads();
  if (threadIdx.x < CH2) {
    int o = threadIdx.x;
    atomicAdd(stats2 + o, (double)((rs[0][o] + rs[1][o]) + (rs[2][o] + rs[3][o])));
  } else if (threadIdx.x < 2*CH2) {
    int o = threadIdx.x - CH2;
    atomicAdd(stats2 + CH2 + o, (double)((rq[0][o] + rq[1][o]) + (rq[2][o] + rq[3][o])));
  }
}

// final: derive sc2 per block, recompute y, apply BN2 + ELU. 8 queries/block,
// thread = (query, out-channel) -> coalesced stores.
__global__ __launch_bounds__(256) void out_kernel(const float* __restrict__ p,
                                                  const float* __restrict__ minq,
                                                  const float* __restrict__ sc1,
                                                  const float* __restrict__ W2,
                                                  const float* __restrict__ b2,
                                                  const double* __restrict__ stats2,
                                                  const float* __restrict__ gamma2,
                                                  const float* __restrict__ beta2,
                                                  float* __restrict__ out) {
  __shared__ float me_lds[8][CH1];
  __shared__ float s2s[CH2], s2h[CH2];
  const int t = threadIdx.x;
  if (t < CH2) {
    double cnt  = (double)NB * NP;
    double mean = stats2[t] / cnt;
    double var  = stats2[CH2 + t] / cnt - mean * mean;
    float vf    = (float)var + BN_EPS;
    float scale = gamma2[t] / sqrtf(vf);
    s2s[t] = scale; s2h[t] = beta2[t] - (float)mean * scale;
  }
  const int qbase = blockIdx.x * 8;
  if (t < 48) {
    int qs = t / 6, c = t % 6;
    int qi = qbase + qs;
    float mval = p[qi*CH1 + c] - minq[qi*CH1 + c];
    float v = fmaf(sc1[c], mval, sc1[CH1 + c]);
    me_lds[qs][c] = v > 0.f ? v : expm1f(v);
  }
  __syncthreads();
  const int qs = t >> 5, o = t & 31;
  const int qi = qbase + qs;
  float y = b2[o];
#pragma unroll
  for (int c = 0; c < CH1; ++c) y = fmaf(me_lds[qs][c], W2[c*CH2 + o], y);
  float r = fmaf(s2s[o], y, s2h[o]);
  out[(size_t)qi*CH2 + o] = r > 0.f ? r : expm1f(r);
}

extern "C" void kernel_launch(void* const* d_in, const int* in_sizes, int n_in,
                              void* d_out, int out_size, void* d_ws, size_t ws_size,
                              hipStream_t stream) {
  const float* x      = (const float*)d_in[0];
  const float* W1     = (const float*)d_in[1];
  const float* b1     = (const float*)d_in[2];
  const float* gamma1 = (const float*)d_in[3];
  const float* beta1  = (const float*)d_in[4];
  const float* W2     = (const float*)d_in[5];
  const float* b2     = (const float*)d_in[6];
  const float* gamma2 = (const float*)d_in[7];
  const float* beta2  = (const float*)d_in[8];
  float* out = (float*)d_out;
  char* ws = (char*)d_ws;

  double* stats2 = (double*)(ws + OFF_STATS2);
  float* sc1  = (float*)(ws + OFF_SC1);
  float* p    = (float*)(ws + OFF_P);
  float* minq = (float*)(ws + OFF_MINQ);
  float* part = (float*)(ws + OFF_PART);

  hipMemsetAsync(ws, 0, 512, stream);  // zero BN2 stat accumulators

  knn_kernel       <<<dim3(NBLK),         dim3(512), 0, stream>>>(x, W1, b1, p, minq, part);
  reduce_fin1_kernel<<<dim3(1),           dim3(768), 0, stream>>>(part, gamma1, beta1, sc1);
  stage2_kernel    <<<dim3(NB*NP/256),    dim3(256), 0, stream>>>(p, minq, sc1, W2, b2, stats2);
  out_kernel       <<<dim3(NB*NP/8),      dim3(256), 0, stream>>>(p, minq, sc1, W2, b2,
                                                                  stats2, gamma2, beta2, out);
}